// Round 12
// baseline (284.766 us; speedup 1.0000x reference)
//
#include <hip/hip_runtime.h>
#include <hip/hip_bf16.h>
#include <math.h>

#define N_NODES 10000
#define N_EDGES 160000
#define D 512
#define DIN 20
#define B 64
#define KC 10
#define DH 256
#define NROW (B*KC)   // 640
#define BN_EPS 1e-5f

#define ZCOUNT 36352            // csum1,csq1,csum2,csq2 (2048) + s1..q3 (1536) + qemb (32768)
#define Z4 (ZCOUNT/4)           // 9088
#define D4 (N_NODES/4)          // 2500
#define IM_ROWS 8
#define IM_UNITS (N_NODES/IM_ROWS)  // 1250
#define DEG_BLOCKS 625
#define GWAVES 4
#define GBLOCKS 2500            // 10000 waves: 1 node per wave, ~10 blocks/CU
#define F1_NS 6
#define F1_ROWS 8
#define F1_KS 256
#define FM_ROWS 4
#define FM_KS 128
#define FM_NS 2

struct P {
  const float *x, *pg, *neigh, *Winit, *binit;
  const float *g1, *be1, *g2, *be2;
  const float *Wfc, *bfc, *W2, *b2, *W3, *b3, *W4, *b4;
  const float *gbA, *bbA, *gbB, *bbB, *gbC, *bbC;
  const int *esrc, *edst, *n2g;
  unsigned short *hb0, *hb1, *hb2;
  float *zbuf, *csum1, *csq1, *csum2, *csq2;
  float *s1,*q1,*s2,*q2,*s3,*q3, *qemb;
  float *G1,*G2,*G3,*part;
  int *degi,*rowstart,*cursor,*csr,*gstart;
  float *out;
};

__device__ __forceinline__ void f4acc(float4& a, const float4 v){
  a.x += v.x; a.y += v.y; a.z += v.z; a.w += v.w;
}
__device__ __forceinline__ void mk_affine(const float4 s, const float4 q, const float4 g,
                                          const float4 b, float4& sc, float4& sh){
  const float invN = 1.0f/(float)N_NODES;
  float mu, var, rs;
  mu = s.x*invN; var = q.x*invN - mu*mu; rs = rsqrtf(var+BN_EPS); sc.x = rs*g.x; sh.x = b.x - mu*sc.x;
  mu = s.y*invN; var = q.y*invN - mu*mu; rs = rsqrtf(var+BN_EPS); sc.y = rs*g.y; sh.y = b.y - mu*sc.y;
  mu = s.z*invN; var = q.z*invN - mu*mu; rs = rsqrtf(var+BN_EPS); sc.z = rs*g.z; sh.z = b.z - mu*sc.z;
  mu = s.w*invN; var = q.w*invN - mu*mu; rs = rsqrtf(var+BN_EPS); sc.w = rs*g.w; sh.w = b.w - mu*sc.w;
}
__device__ __forceinline__ float4 aff_relu(const float4 v, const float4 sc, const float4 sh){
  float4 o;
  o.x = fmaxf(fmaf(v.x, sc.x, sh.x), 0.0f);
  o.y = fmaxf(fmaf(v.y, sc.y, sh.y), 0.0f);
  o.z = fmaxf(fmaf(v.z, sc.z, sh.z), 0.0f);
  o.w = fmaxf(fmaf(v.w, sc.w, sh.w), 0.0f);
  return o;
}
__device__ __forceinline__ void bf_unpack(const uint4 u, float4& lo, float4& hi){
  lo.x = __uint_as_float(u.x << 16); lo.y = __uint_as_float(u.x & 0xffff0000u);
  lo.z = __uint_as_float(u.y << 16); lo.w = __uint_as_float(u.y & 0xffff0000u);
  hi.x = __uint_as_float(u.z << 16); hi.y = __uint_as_float(u.z & 0xffff0000u);
  hi.z = __uint_as_float(u.w << 16); hi.w = __uint_as_float(u.w & 0xffff0000u);
}
__device__ __forceinline__ unsigned bf_pack2(float a, float b){ // RNE
  unsigned ua = __float_as_uint(a); ua = (ua + 0x7fffu + ((ua>>16)&1u)) >> 16;
  unsigned ub = __float_as_uint(b); ub = (ub + 0x7fffu + ((ub>>16)&1u)) & 0xffff0000u;
  return (ua & 0xffffu) | ub;
}
__device__ __forceinline__ unsigned short bf_pack1(float a){
  unsigned ua = __float_as_uint(a); return (unsigned short)((ua + 0x7fffu + ((ua>>16)&1u)) >> 16);
}

// ================= gather (batch-8, shfl broadcast, 1 node/wave) =================
template<bool FUSED>
__device__ __forceinline__ void gather_body(const P& p,
    const unsigned short* __restrict__ hin, unsigned short* __restrict__ hout,
    const float* pcs, const float* pcq, const float* pgm, const float* pbt,
    float* cs, float* cq, float* red){
  int t = threadIdx.x;
  int lane = t & 63;
  int wave = t >> 6;
  int wid  = blockIdx.x*GWAVES + wave;
  int tot  = gridDim.x*GWAVES;
  const uint4* hb4 = (const uint4*)hin;   // row stride = 64 uint4
  float4 scA, shA, scB, shB;
  if (FUSED){
    mk_affine(((const float4*)pcs)[2*lane],   ((const float4*)pcq)[2*lane],
              ((const float4*)pgm)[2*lane],   ((const float4*)pbt)[2*lane],   scA, shA);
    mk_affine(((const float4*)pcs)[2*lane+1], ((const float4*)pcq)[2*lane+1],
              ((const float4*)pgm)[2*lane+1], ((const float4*)pbt)[2*lane+1], scB, shB);
  }
  float4 sLo = make_float4(0,0,0,0), sHi = make_float4(0,0,0,0);
  float4 qLo = make_float4(0,0,0,0), qHi = make_float4(0,0,0,0);
  for (int node = wid; node < N_NODES; node += tot){
    int start = p.rowstart[node], end = p.rowstart[node+1];
    float4 aLo = make_float4(0,0,0,0), aHi = make_float4(0,0,0,0);
    float4 bLo = make_float4(0,0,0,0), bHi = make_float4(0,0,0,0);
    for (int base = start; base < end; base += 64){
      int cnt = end - base; if (cnt > 64) cnt = 64;
      int myidx = (lane < cnt) ? p.csr[base+lane] : 0;
      int j = 0;
      for (; j+8 <= cnt; j += 8){
        uint4 u[8];
        #pragma unroll
        for (int k = 0; k < 8; ++k){
          int idx = __shfl(myidx, j+k, 64);
          u[k] = hb4[(size_t)idx*64 + lane];
        }
        #pragma unroll
        for (int k = 0; k < 8; ++k){
          float4 lo, hi; bf_unpack(u[k], lo, hi);
          if (FUSED){ lo = aff_relu(lo, scA, shA); hi = aff_relu(hi, scB, shB); }
          if (k & 1){ f4acc(bLo, lo); f4acc(bHi, hi); }
          else      { f4acc(aLo, lo); f4acc(aHi, hi); }
        }
      }
      for (; j < cnt; ++j){
        int idx = __shfl(myidx, j, 64);
        uint4 u0 = hb4[(size_t)idx*64 + lane];
        float4 lo, hi; bf_unpack(u0, lo, hi);
        if (FUSED){ lo = aff_relu(lo, scA, shA); hi = aff_relu(hi, scB, shB); }
        f4acc(aLo, lo); f4acc(aHi, hi);
      }
    }
    float inv = 1.0f/fmaxf((float)(end-start), 1.0f);
    uint4 us = hb4[(size_t)node*64 + lane];
    float4 hLo, hHi; bf_unpack(us, hLo, hHi);
    if (FUSED){ hLo = aff_relu(hLo, scA, shA); hHi = aff_relu(hHi, scB, shB); }
    float4 oLo, oHi;
    oLo.x = hLo.x + (aLo.x+bLo.x)*inv;  oLo.y = hLo.y + (aLo.y+bLo.y)*inv;
    oLo.z = hLo.z + (aLo.z+bLo.z)*inv;  oLo.w = hLo.w + (aLo.w+bLo.w)*inv;
    oHi.x = hHi.x + (aHi.x+bHi.x)*inv;  oHi.y = hHi.y + (aHi.y+bHi.y)*inv;
    oHi.z = hHi.z + (aHi.z+bHi.z)*inv;  oHi.w = hHi.w + (aHi.w+bHi.w)*inv;
    uint4 ou;
    ou.x = bf_pack2(oLo.x, oLo.y); ou.y = bf_pack2(oLo.z, oLo.w);
    ou.z = bf_pack2(oHi.x, oHi.y); ou.w = bf_pack2(oHi.z, oHi.w);
    ((uint4*)hout)[(size_t)node*64 + lane] = ou;
    f4acc(sLo, oLo); f4acc(sHi, oHi);
    qLo.x += oLo.x*oLo.x; qLo.y += oLo.y*oLo.y; qLo.z += oLo.z*oLo.z; qLo.w += oLo.w*oLo.w;
    qHi.x += oHi.x*oHi.x; qHi.y += oHi.y*oHi.y; qHi.z += oHi.z*oHi.z; qHi.w += oHi.w*oHi.w;
  }
  float* my = red + wave*1024;
  int c = 8*lane;
  *((float4*)&my[c])      = sLo;  *((float4*)&my[c+4])     = sHi;
  *((float4*)&my[512+c])  = qLo;  *((float4*)&my[512+c+4]) = qHi;
  __syncthreads();
  for (int e = t; e < 1024; e += 256){
    float v = red[e] + red[1024+e] + red[2048+e] + red[3072+e];
    if (e < 512) atomicAdd(&cs[e], v);
    else         atomicAdd(&cq[e-512], v);
  }
}

// ================= kernels =================
__global__ __launch_bounds__(256) void k_setup(P p){
  int b = blockIdx.x, nb = gridDim.x, t = threadIdx.x;
  for (int i4 = b*256 + t; i4 < Z4 + D4; i4 += nb*256){
    if (i4 < Z4) ((float4*)p.zbuf)[i4] = make_float4(0.f,0.f,0.f,0.f);
    else         ((int4*)p.degi)[i4 - Z4] = make_int4(0,0,0,0);
  }
  if (b == 0 && t <= B){
    int lo = 0, hi = N_NODES;
    while (lo < hi){ int mid = (lo+hi)>>1; if (p.n2g[mid] < t) lo = mid+1; else hi = mid; }
    p.gstart[t] = lo;
  }
}

// fused: blocks [0,625) degree histogram; blocks [625,1875) init projection (W in regs)
__global__ __launch_bounds__(256) void k_deg_init(P p){
  __shared__ float xs[IM_ROWS*DIN];
  int t = threadIdx.x;
  if (blockIdx.x < DEG_BLOCKS){
    int e = blockIdx.x*256 + t;
    if (e < N_EDGES) atomicAdd(&p.degi[p.edst[e]], 1);
    return;
  }
  int unit = blockIdx.x - DEG_BLOCKS;   // 0..1249
  float wlo[DIN], whi[DIN];
  #pragma unroll
  for (int k = 0; k < DIN; ++k){ wlo[k] = p.Winit[k*D + t]; whi[k] = p.Winit[k*D + t + 256]; }
  float b0 = p.binit[t], b1 = p.binit[t+256];
  int r0 = unit*IM_ROWS;
  for (int i = t; i < IM_ROWS*DIN; i += 256) xs[i] = p.x[(size_t)r0*DIN + i];
  __syncthreads();
  for (int rr = 0; rr < IM_ROWS; ++rr){
    float a0 = b0, a1 = b1;
    #pragma unroll
    for (int k = 0; k < DIN; ++k){
      float xv = xs[rr*DIN + k];
      a0 += xv*wlo[k]; a1 += xv*whi[k];
    }
    p.hb0[(size_t)(r0+rr)*D + t]       = bf_pack1(a0);
    p.hb0[(size_t)(r0+rr)*D + t + 256] = bf_pack1(a1);
  }
}

__global__ __launch_bounds__(256) void k_scan(P p){
  __shared__ int part[256];
  int t = threadIdx.x;
  const int PER = (N_NODES + 255)/256; // 40
  int base = t*PER;
  int s = 0;
  for (int i = 0; i < PER; ++i){ int idx = base+i; if (idx < N_NODES) s += p.degi[idx]; }
  part[t] = s;
  __syncthreads();
  for (int off = 1; off < 256; off <<= 1){
    int v = (t >= off) ? part[t-off] : 0;
    __syncthreads();
    part[t] += v;
    __syncthreads();
  }
  int run = (t > 0) ? part[t-1] : 0;
  for (int i = 0; i < PER; ++i){
    int idx = base+i;
    if (idx < N_NODES){ p.rowstart[idx] = run; p.cursor[idx] = run; run += p.degi[idx]; }
  }
  if (t == 255) p.rowstart[N_NODES] = run;
}

__global__ __launch_bounds__(256) void k_fill(P p){
  int e = blockIdx.x*256 + threadIdx.x;
  if (e < N_EDGES){
    int pos = atomicAdd(&p.cursor[p.edst[e]], 1);
    p.csr[pos] = p.esrc[e];
  }
}

__global__ __launch_bounds__(256) void k_g1(P p){
  __shared__ float red[4096];
  gather_body<false>(p, p.hb0, p.hb1, nullptr,nullptr,nullptr,nullptr, p.csum1, p.csq1, red);
}
__global__ __launch_bounds__(256) void k_g2(P p){
  __shared__ float red[4096];
  gather_body<true>(p, p.hb1, p.hb2, p.csum1, p.csq1, p.g1, p.be1, p.csum2, p.csq2, red);
}

__global__ __launch_bounds__(256) void k_readout(P p){
  __shared__ float red[2048];
  int g = blockIdx.x >> 4, chunk = blockIdx.x & 15;
  int t = threadIdx.x;
  int lane = t & 63, wave = t >> 6;
  const uint4* hb4 = (const uint4*)p.hb2;
  float4 scA, shA, scB, shB;
  mk_affine(((const float4*)p.csum2)[2*lane],   ((const float4*)p.csq2)[2*lane],
            ((const float4*)p.g2)[2*lane],      ((const float4*)p.be2)[2*lane],   scA, shA);
  mk_affine(((const float4*)p.csum2)[2*lane+1], ((const float4*)p.csq2)[2*lane+1],
            ((const float4*)p.g2)[2*lane+1],    ((const float4*)p.be2)[2*lane+1], scB, shB);
  int s = p.gstart[g], e = p.gstart[g+1];
  int rows = e - s;
  int per = (rows + 15)/16;
  int r0 = s + chunk*per;
  int r1 = r0 + per; if (r1 > e) r1 = e;
  float4 aLo = make_float4(0,0,0,0), aHi = make_float4(0,0,0,0);
  for (int r = r0 + wave; r < r1; r += 4){
    uint4 u = hb4[(size_t)r*64 + lane];
    float4 lo, hi; bf_unpack(u, lo, hi);
    lo = aff_relu(lo, scA, shA); hi = aff_relu(hi, scB, shB);
    f4acc(aLo, lo); f4acc(aHi, hi);
  }
  int c = 8*lane;
  *((float4*)&red[wave*512 + c])     = aLo;
  *((float4*)&red[wave*512 + c + 4]) = aHi;
  __syncthreads();
  for (int e2 = t; e2 < 512; e2 += 256){
    float v = red[e2] + red[512+e2] + red[1024+e2] + red[1536+e2];
    atomicAdd(&p.qemb[(size_t)g*D + e2], v);
  }
}

// ---- FC1 partials: [640,1536]@[1536,256], K split 6x256 ----
__global__ __launch_bounds__(256) void k_fc1(P p){
  __shared__ float brow[F1_ROWS*F1_KS];
  int t = threadIdx.x;
  int rb = blockIdx.x % 80, ks = blockIdx.x / 80;
  int r0 = rb*F1_ROWS, k0 = ks*F1_KS;
  for (int rr = 0; rr < F1_ROWS; ++rr){
    int r = r0+rr;
    int g = r/KC, k = r - g*KC;
    int j = k0 + t;
    float v;
    if (j < D){
      float invc = 1.0f/fmaxf((float)(p.gstart[g+1]-p.gstart[g]), 1.0f);
      v = p.qemb[(size_t)g*D + j]*invc;
    } else if (j < 2*D){
      v = p.pg[(size_t)g*D + (j-D)];
    } else {
      v = p.neigh[((size_t)g*KC + k)*D + (j-2*D)];
    }
    brow[rr*F1_KS + t] = v;
  }
  __syncthreads();
  float acc[F1_ROWS] = {0.f,0.f,0.f,0.f,0.f,0.f,0.f,0.f};
  #pragma unroll 4
  for (int kk = 0; kk < F1_KS; ++kk){
    float w = p.Wfc[(size_t)(k0+kk)*DH + t];
    #pragma unroll
    for (int rr = 0; rr < F1_ROWS; ++rr) acc[rr] += brow[rr*F1_KS + kk]*w;
  }
  for (int rr = 0; rr < F1_ROWS; ++rr)
    p.part[((size_t)ks*NROW + r0+rr)*DH + t] = acc[rr];
}

// ---- reduce partials + bias, write out, accumulate BN stats ----
__global__ __launch_bounds__(256) void k_reduce(P p, const float* bias, float* outG,
                                                float* s, float* q, int nslice){
  int t = threadIdx.x;
  int r0 = blockIdx.x*8;
  float bval = bias[t];
  float ls = 0.f, lq = 0.f;
  for (int rr = 0; rr < 8; ++rr){
    int r = r0+rr;
    float acc = bval;
    for (int sl = 0; sl < nslice; ++sl) acc += p.part[((size_t)sl*NROW + r)*DH + t];
    outG[(size_t)r*DH + t] = acc;
    ls += acc; lq += acc*acc;
  }
  atomicAdd(&s[t], ls); atomicAdd(&q[t], lq);
}

// ---- FC mid partials: BN(prev)+relu staged, K split 2x128 ----
__global__ __launch_bounds__(256) void k_fcmid(P p, const float* in, const float* ps,
    const float* pq, const float* gamma, const float* beta, const float* W){
  __shared__ float row[FM_ROWS*FM_KS];
  int t = threadIdx.x;
  int r0 = blockIdx.x*FM_ROWS;
  int k0 = blockIdx.y*FM_KS;
  const float invM = 1.0f/(float)NROW;
  #pragma unroll
  for (int i = 0; i < 2; ++i){
    int idx = t + i*256;          // 0..511
    int rr = idx >> 7, kk = idx & 127;
    int c = k0 + kk;
    float mu = ps[c]*invM;
    float var = pq[c]*invM - mu*mu;
    float rs = rsqrtf(var + BN_EPS);
    float v = in[(size_t)(r0+rr)*DH + c];
    row[rr*FM_KS + kk] = fmaxf((v-mu)*rs*gamma[c] + beta[c], 0.0f);
  }
  __syncthreads();
  float acc[FM_ROWS] = {0.f,0.f,0.f,0.f};
  #pragma unroll 4
  for (int kk = 0; kk < FM_KS; ++kk){
    float w = W[(size_t)(k0+kk)*DH + t];
    #pragma unroll
    for (int rr = 0; rr < FM_ROWS; ++rr) acc[rr] += row[rr*FM_KS + kk]*w;
  }
  for (int rr = 0; rr < FM_ROWS; ++rr)
    p.part[((size_t)blockIdx.y*NROW + r0+rr)*DH + t] = acc[rr];
}

__global__ __launch_bounds__(256) void k_final(P p){
  int t = threadIdx.x;
  int wave = t>>6, lane = t&63;
  int r = blockIdx.x*4 + wave;
  const float invM = 1.0f/(float)NROW;
  float sum = 0.f;
  #pragma unroll
  for (int j = 0; j < 4; ++j){
    int c = lane + 64*j;
    float mu = p.s3[c]*invM;
    float var = p.q3[c]*invM - mu*mu;
    float rs = rsqrtf(var+BN_EPS);
    float v = p.G3[(size_t)r*DH + c];
    v = fmaxf((v-mu)*rs*p.gbC[c] + p.bbC[c], 0.0f);
    sum += v*p.W4[c];
  }
  #pragma unroll
  for (int off = 32; off > 0; off >>= 1) sum += __shfl_down(sum, off, 64);
  if (lane == 0){
    float z = sum + p.b4[0];
    p.out[r] = 1.0f/(1.0f + expf(-z));
  }
}

extern "C" void kernel_launch(void* const* d_in, const int* in_sizes, int n_in,
                              void* d_out, int out_size, void* d_ws, size_t ws_size,
                              hipStream_t stream) {
  P p;
  p.x     = (const float*)d_in[0];
  p.pg    = (const float*)d_in[1];
  p.neigh = (const float*)d_in[2];
  p.Winit = (const float*)d_in[3];
  p.binit = (const float*)d_in[4];
  p.g1    = (const float*)d_in[5];
  p.be1   = (const float*)d_in[6];
  p.g2    = (const float*)d_in[7];
  p.be2   = (const float*)d_in[8];
  p.Wfc   = (const float*)d_in[9];
  p.bfc   = (const float*)d_in[10];
  p.W2    = (const float*)d_in[11];
  p.b2    = (const float*)d_in[12];
  p.W3    = (const float*)d_in[13];
  p.b3    = (const float*)d_in[14];
  p.W4    = (const float*)d_in[15];
  p.b4    = (const float*)d_in[16];
  p.gbA   = (const float*)d_in[17];
  p.bbA   = (const float*)d_in[18];
  p.gbB   = (const float*)d_in[19];
  p.bbB   = (const float*)d_in[20];
  p.gbC   = (const float*)d_in[21];
  p.bbC   = (const float*)d_in[22];
  p.esrc  = (const int*)d_in[23];
  p.edst  = (const int*)d_in[24];
  p.n2g   = (const int*)d_in[25];
  p.out   = (float*)d_out;

  float* ws = (float*)d_ws;
  size_t off = 0;
  p.hb0 = (unsigned short*)(ws + off); off += (size_t)N_NODES*D/2;
  p.hb1 = (unsigned short*)(ws + off); off += (size_t)N_NODES*D/2;
  p.hb2 = (unsigned short*)(ws + off); off += (size_t)N_NODES*D/2;
  p.zbuf  = ws + off;                 // zero region start
  p.csum1 = ws + off; off += 512;
  p.csq1  = ws + off; off += 512;
  p.csum2 = ws + off; off += 512;
  p.csq2  = ws + off; off += 512;
  p.s1    = ws + off; off += 256;
  p.q1    = ws + off; off += 256;
  p.s2    = ws + off; off += 256;
  p.q2    = ws + off; off += 256;
  p.s3    = ws + off; off += 256;
  p.q3    = ws + off; off += 256;
  p.qemb  = ws + off; off += (size_t)B*D;   // end zero region (ZCOUNT floats total)
  p.G1   = ws + off; off += (size_t)NROW*DH;
  p.G2   = ws + off; off += (size_t)NROW*DH;
  p.G3   = ws + off; off += (size_t)NROW*DH;
  p.part = ws + off; off += (size_t)F1_NS*NROW*DH;
  p.degi     = (int*)(ws + off); off += N_NODES;
  p.rowstart = (int*)(ws + off); off += N_NODES + 1;
  p.cursor   = (int*)(ws + off); off += N_NODES;
  p.csr      = (int*)(ws + off); off += N_EDGES;
  p.gstart   = (int*)(ws + off); off += B + 1;

  k_setup<<<64, 256, 0, stream>>>(p);
  k_deg_init<<<DEG_BLOCKS + IM_UNITS, 256, 0, stream>>>(p);
  k_scan<<<1, 256, 0, stream>>>(p);
  k_fill<<<(N_EDGES+255)/256, 256, 0, stream>>>(p);
  k_g1<<<GBLOCKS, 256, 0, stream>>>(p);
  k_g2<<<GBLOCKS, 256, 0, stream>>>(p);
  k_readout<<<1024, 256, 0, stream>>>(p);
  k_fc1<<<480, 256, 0, stream>>>(p);
  k_reduce<<<NROW/8, 256, 0, stream>>>(p, p.bfc, p.G1, p.s1, p.q1, F1_NS);
  k_fcmid<<<dim3(NROW/FM_ROWS, FM_NS), 256, 0, stream>>>(p, p.G1, p.s1, p.q1, p.gbA, p.bbA, p.W2);
  k_reduce<<<NROW/8, 256, 0, stream>>>(p, p.b2, p.G2, p.s2, p.q2, FM_NS);
  k_fcmid<<<dim3(NROW/FM_ROWS, FM_NS), 256, 0, stream>>>(p, p.G2, p.s2, p.q2, p.gbB, p.bbB, p.W3);
  k_reduce<<<NROW/8, 256, 0, stream>>>(p, p.b3, p.G3, p.s3, p.q3, FM_NS);
  k_final<<<NROW/4, 256, 0, stream>>>(p);
}

// Round 13
// 213.001 us; speedup vs baseline: 1.3369x; 1.3369x over previous
//
#include <hip/hip_runtime.h>
#include <hip/hip_bf16.h>
#include <math.h>

#define N_NODES 10000
#define N_EDGES 160000
#define D 512
#define DIN 20
#define B 64
#define KC 10
#define DH 256
#define NROW (B*KC)   // 640
#define BN_EPS 1e-5f

#define ZCOUNT 36356            // csum/csq (2048) + s1..q3 (1536) + qemb (32768) + bar (4)
#define Z4 (ZCOUNT/4)           // 9089
#define D4 (N_NODES/4)          // 2500
#define IM_ROWS 8
#define IM_UNITS (N_NODES/IM_ROWS)  // 1250
#define DEG_BLOCKS 625
#define GWAVES 4
#define GBLOCKS 625             // 2500 waves, 4 nodes each (min stats-epilogue atomics)
#define F1_NS 6
#define F1_ROWS 8
#define F1_KS 256
#define TB 160                  // persistent tail blocks (<=256 CUs -> co-resident)

struct P {
  const float *x, *pg, *neigh, *Winit, *binit;
  const float *g1, *be1, *g2, *be2;
  const float *Wfc, *bfc, *W2, *b2, *W3, *b3, *W4, *b4;
  const float *gbA, *bbA, *gbB, *bbB, *gbC, *bbC;
  const int *esrc, *edst, *n2g;
  unsigned short *hb0, *hb1, *hb2;
  float *zbuf, *csum1, *csq1, *csum2, *csq2;
  float *s1,*q1,*s2,*q2,*s3,*q3, *qemb;
  int *bar;
  float *G1,*G2,*G3,*part;
  int *degi,*rowstart,*cursor,*csr,*gstart;
  float *out;
};

__device__ __forceinline__ void f4acc(float4& a, const float4 v){
  a.x += v.x; a.y += v.y; a.z += v.z; a.w += v.w;
}
__device__ __forceinline__ void mk_affine(const float4 s, const float4 q, const float4 g,
                                          const float4 b, float4& sc, float4& sh){
  const float invN = 1.0f/(float)N_NODES;
  float mu, var, rs;
  mu = s.x*invN; var = q.x*invN - mu*mu; rs = rsqrtf(var+BN_EPS); sc.x = rs*g.x; sh.x = b.x - mu*sc.x;
  mu = s.y*invN; var = q.y*invN - mu*mu; rs = rsqrtf(var+BN_EPS); sc.y = rs*g.y; sh.y = b.y - mu*sc.y;
  mu = s.z*invN; var = q.z*invN - mu*mu; rs = rsqrtf(var+BN_EPS); sc.z = rs*g.z; sh.z = b.z - mu*sc.z;
  mu = s.w*invN; var = q.w*invN - mu*mu; rs = rsqrtf(var+BN_EPS); sc.w = rs*g.w; sh.w = b.w - mu*sc.w;
}
__device__ __forceinline__ float4 aff_relu(const float4 v, const float4 sc, const float4 sh){
  float4 o;
  o.x = fmaxf(fmaf(v.x, sc.x, sh.x), 0.0f);
  o.y = fmaxf(fmaf(v.y, sc.y, sh.y), 0.0f);
  o.z = fmaxf(fmaf(v.z, sc.z, sh.z), 0.0f);
  o.w = fmaxf(fmaf(v.w, sc.w, sh.w), 0.0f);
  return o;
}
__device__ __forceinline__ void bf_unpack(const uint4 u, float4& lo, float4& hi){
  lo.x = __uint_as_float(u.x << 16); lo.y = __uint_as_float(u.x & 0xffff0000u);
  lo.z = __uint_as_float(u.y << 16); lo.w = __uint_as_float(u.y & 0xffff0000u);
  hi.x = __uint_as_float(u.z << 16); hi.y = __uint_as_float(u.z & 0xffff0000u);
  hi.z = __uint_as_float(u.w << 16); hi.w = __uint_as_float(u.w & 0xffff0000u);
}
__device__ __forceinline__ unsigned bf_pack2(float a, float b){ // RNE
  unsigned ua = __float_as_uint(a); ua = (ua + 0x7fffu + ((ua>>16)&1u)) >> 16;
  unsigned ub = __float_as_uint(b); ub = (ub + 0x7fffu + ((ub>>16)&1u)) & 0xffff0000u;
  return (ua & 0xffffu) | ub;
}
__device__ __forceinline__ unsigned short bf_pack1(float a){
  unsigned ua = __float_as_uint(a); return (unsigned short)((ua + 0x7fffu + ((ua>>16)&1u)) >> 16);
}

// ================= gather (batch-8, shfl broadcast, 4 nodes/wave) =================
template<bool FUSED>
__device__ __forceinline__ void gather_body(const P& p,
    const unsigned short* __restrict__ hin, unsigned short* __restrict__ hout,
    const float* pcs, const float* pcq, const float* pgm, const float* pbt,
    float* cs, float* cq, float* red){
  int t = threadIdx.x;
  int lane = t & 63;
  int wave = t >> 6;
  int wid  = blockIdx.x*GWAVES + wave;
  int tot  = gridDim.x*GWAVES;
  const uint4* hb4 = (const uint4*)hin;   // row stride = 64 uint4
  float4 scA, shA, scB, shB;
  if (FUSED){
    mk_affine(((const float4*)pcs)[2*lane],   ((const float4*)pcq)[2*lane],
              ((const float4*)pgm)[2*lane],   ((const float4*)pbt)[2*lane],   scA, shA);
    mk_affine(((const float4*)pcs)[2*lane+1], ((const float4*)pcq)[2*lane+1],
              ((const float4*)pgm)[2*lane+1], ((const float4*)pbt)[2*lane+1], scB, shB);
  }
  float4 sLo = make_float4(0,0,0,0), sHi = make_float4(0,0,0,0);
  float4 qLo = make_float4(0,0,0,0), qHi = make_float4(0,0,0,0);
  for (int node = wid; node < N_NODES; node += tot){
    int start = p.rowstart[node], end = p.rowstart[node+1];
    float4 aLo = make_float4(0,0,0,0), aHi = make_float4(0,0,0,0);
    float4 bLo = make_float4(0,0,0,0), bHi = make_float4(0,0,0,0);
    for (int base = start; base < end; base += 64){
      int cnt = end - base; if (cnt > 64) cnt = 64;
      int myidx = (lane < cnt) ? p.csr[base+lane] : 0;
      int j = 0;
      for (; j+8 <= cnt; j += 8){
        uint4 u[8];
        #pragma unroll
        for (int k = 0; k < 8; ++k){
          int idx = __shfl(myidx, j+k, 64);
          u[k] = hb4[(size_t)idx*64 + lane];
        }
        #pragma unroll
        for (int k = 0; k < 8; ++k){
          float4 lo, hi; bf_unpack(u[k], lo, hi);
          if (FUSED){ lo = aff_relu(lo, scA, shA); hi = aff_relu(hi, scB, shB); }
          if (k & 1){ f4acc(bLo, lo); f4acc(bHi, hi); }
          else      { f4acc(aLo, lo); f4acc(aHi, hi); }
        }
      }
      for (; j < cnt; ++j){
        int idx = __shfl(myidx, j, 64);
        uint4 u0 = hb4[(size_t)idx*64 + lane];
        float4 lo, hi; bf_unpack(u0, lo, hi);
        if (FUSED){ lo = aff_relu(lo, scA, shA); hi = aff_relu(hi, scB, shB); }
        f4acc(aLo, lo); f4acc(aHi, hi);
      }
    }
    float inv = 1.0f/fmaxf((float)(end-start), 1.0f);
    uint4 us = hb4[(size_t)node*64 + lane];
    float4 hLo, hHi; bf_unpack(us, hLo, hHi);
    if (FUSED){ hLo = aff_relu(hLo, scA, shA); hHi = aff_relu(hHi, scB, shB); }
    float4 oLo, oHi;
    oLo.x = hLo.x + (aLo.x+bLo.x)*inv;  oLo.y = hLo.y + (aLo.y+bLo.y)*inv;
    oLo.z = hLo.z + (aLo.z+bLo.z)*inv;  oLo.w = hLo.w + (aLo.w+bLo.w)*inv;
    oHi.x = hHi.x + (aHi.x+bHi.x)*inv;  oHi.y = hHi.y + (aHi.y+bHi.y)*inv;
    oHi.z = hHi.z + (aHi.z+bHi.z)*inv;  oHi.w = hHi.w + (aHi.w+bHi.w)*inv;
    uint4 ou;
    ou.x = bf_pack2(oLo.x, oLo.y); ou.y = bf_pack2(oLo.z, oLo.w);
    ou.z = bf_pack2(oHi.x, oHi.y); ou.w = bf_pack2(oHi.z, oHi.w);
    ((uint4*)hout)[(size_t)node*64 + lane] = ou;
    f4acc(sLo, oLo); f4acc(sHi, oHi);
    qLo.x += oLo.x*oLo.x; qLo.y += oLo.y*oLo.y; qLo.z += oLo.z*oLo.z; qLo.w += oLo.w*oLo.w;
    qHi.x += oHi.x*oHi.x; qHi.y += oHi.y*oHi.y; qHi.z += oHi.z*oHi.z; qHi.w += oHi.w*oHi.w;
  }
  float* my = red + wave*1024;
  int c = 8*lane;
  *((float4*)&my[c])      = sLo;  *((float4*)&my[c+4])     = sHi;
  *((float4*)&my[512+c])  = qLo;  *((float4*)&my[512+c+4]) = qHi;
  __syncthreads();
  for (int e = t; e < 1024; e += 256){
    float v = red[e] + red[1024+e] + red[2048+e] + red[3072+e];
    if (e < 512) atomicAdd(&cs[e], v);
    else         atomicAdd(&cq[e-512], v);
  }
}

// ================= kernels =================
__global__ __launch_bounds__(256) void k_setup(P p){
  int b = blockIdx.x, nb = gridDim.x, t = threadIdx.x;
  for (int i4 = b*256 + t; i4 < Z4 + D4; i4 += nb*256){
    if (i4 < Z4) ((float4*)p.zbuf)[i4] = make_float4(0.f,0.f,0.f,0.f);
    else         ((int4*)p.degi)[i4 - Z4] = make_int4(0,0,0,0);
  }
  if (b == 0 && t <= B){
    int lo = 0, hi = N_NODES;
    while (lo < hi){ int mid = (lo+hi)>>1; if (p.n2g[mid] < t) lo = mid+1; else hi = mid; }
    p.gstart[t] = lo;
  }
}

// fused: blocks [0,625) degree histogram; blocks [625,1875) init projection (W in regs)
__global__ __launch_bounds__(256) void k_deg_init(P p){
  __shared__ float xs[IM_ROWS*DIN];
  int t = threadIdx.x;
  if (blockIdx.x < DEG_BLOCKS){
    int e = blockIdx.x*256 + t;
    if (e < N_EDGES) atomicAdd(&p.degi[p.edst[e]], 1);
    return;
  }
  int unit = blockIdx.x - DEG_BLOCKS;   // 0..1249
  float wlo[DIN], whi[DIN];
  #pragma unroll
  for (int k = 0; k < DIN; ++k){ wlo[k] = p.Winit[k*D + t]; whi[k] = p.Winit[k*D + t + 256]; }
  float b0 = p.binit[t], b1 = p.binit[t+256];
  int r0 = unit*IM_ROWS;
  for (int i = t; i < IM_ROWS*DIN; i += 256) xs[i] = p.x[(size_t)r0*DIN + i];
  __syncthreads();
  for (int rr = 0; rr < IM_ROWS; ++rr){
    float a0 = b0, a1 = b1;
    #pragma unroll
    for (int k = 0; k < DIN; ++k){
      float xv = xs[rr*DIN + k];
      a0 += xv*wlo[k]; a1 += xv*whi[k];
    }
    p.hb0[(size_t)(r0+rr)*D + t]       = bf_pack1(a0);
    p.hb0[(size_t)(r0+rr)*D + t + 256] = bf_pack1(a1);
  }
}

__global__ __launch_bounds__(256) void k_scan(P p){
  __shared__ int part[256];
  int t = threadIdx.x;
  const int PER = (N_NODES + 255)/256; // 40
  int base = t*PER;
  int s = 0;
  for (int i = 0; i < PER; ++i){ int idx = base+i; if (idx < N_NODES) s += p.degi[idx]; }
  part[t] = s;
  __syncthreads();
  for (int off = 1; off < 256; off <<= 1){
    int v = (t >= off) ? part[t-off] : 0;
    __syncthreads();
    part[t] += v;
    __syncthreads();
  }
  int run = (t > 0) ? part[t-1] : 0;
  for (int i = 0; i < PER; ++i){
    int idx = base+i;
    if (idx < N_NODES){ p.rowstart[idx] = run; p.cursor[idx] = run; run += p.degi[idx]; }
  }
  if (t == 255) p.rowstart[N_NODES] = run;
}

__global__ __launch_bounds__(256) void k_fill(P p){
  int e = blockIdx.x*256 + threadIdx.x;
  if (e < N_EDGES){
    int pos = atomicAdd(&p.cursor[p.edst[e]], 1);
    p.csr[pos] = p.esrc[e];
  }
}

__global__ __launch_bounds__(256) void k_g1(P p){
  __shared__ float red[4096];
  gather_body<false>(p, p.hb0, p.hb1, nullptr,nullptr,nullptr,nullptr, p.csum1, p.csq1, red);
}
__global__ __launch_bounds__(256) void k_g2(P p){
  __shared__ float red[4096];
  gather_body<true>(p, p.hb1, p.hb2, p.csum1, p.csq1, p.g1, p.be1, p.csum2, p.csq2, red);
}

__global__ __launch_bounds__(256) void k_readout(P p){
  __shared__ float red[2048];
  int g = blockIdx.x >> 3, chunk = blockIdx.x & 7;
  int t = threadIdx.x;
  int lane = t & 63, wave = t >> 6;
  const uint4* hb4 = (const uint4*)p.hb2;
  float4 scA, shA, scB, shB;
  mk_affine(((const float4*)p.csum2)[2*lane],   ((const float4*)p.csq2)[2*lane],
            ((const float4*)p.g2)[2*lane],      ((const float4*)p.be2)[2*lane],   scA, shA);
  mk_affine(((const float4*)p.csum2)[2*lane+1], ((const float4*)p.csq2)[2*lane+1],
            ((const float4*)p.g2)[2*lane+1],    ((const float4*)p.be2)[2*lane+1], scB, shB);
  int s = p.gstart[g], e = p.gstart[g+1];
  int rows = e - s;
  int per = (rows + 7)/8;
  int r0 = s + chunk*per;
  int r1 = r0 + per; if (r1 > e) r1 = e;
  float4 aLo = make_float4(0,0,0,0), aHi = make_float4(0,0,0,0);
  for (int r = r0 + wave; r < r1; r += 4){
    uint4 u = hb4[(size_t)r*64 + lane];
    float4 lo, hi; bf_unpack(u, lo, hi);
    lo = aff_relu(lo, scA, shA); hi = aff_relu(hi, scB, shB);
    f4acc(aLo, lo); f4acc(aHi, hi);
  }
  int c = 8*lane;
  *((float4*)&red[wave*512 + c])     = aLo;
  *((float4*)&red[wave*512 + c + 4]) = aHi;
  __syncthreads();
  for (int e2 = t; e2 < 512; e2 += 256){
    float v = red[e2] + red[512+e2] + red[1024+e2] + red[1536+e2];
    atomicAdd(&p.qemb[(size_t)g*D + e2], v);
  }
}

// ---- FC1 partials: [640,1536]@[1536,256], K split 6x256 ----
__global__ __launch_bounds__(256) void k_fc1(P p){
  __shared__ float brow[F1_ROWS*F1_KS];
  int t = threadIdx.x;
  int rb = blockIdx.x % 80, ks = blockIdx.x / 80;
  int r0 = rb*F1_ROWS, k0 = ks*F1_KS;
  for (int rr = 0; rr < F1_ROWS; ++rr){
    int r = r0+rr;
    int g = r/KC, k = r - g*KC;
    int j = k0 + t;
    float v;
    if (j < D){
      float invc = 1.0f/fmaxf((float)(p.gstart[g+1]-p.gstart[g]), 1.0f);
      v = p.qemb[(size_t)g*D + j]*invc;
    } else if (j < 2*D){
      v = p.pg[(size_t)g*D + (j-D)];
    } else {
      v = p.neigh[((size_t)g*KC + k)*D + (j-2*D)];
    }
    brow[rr*F1_KS + t] = v;
  }
  __syncthreads();
  float acc[F1_ROWS] = {0.f,0.f,0.f,0.f,0.f,0.f,0.f,0.f};
  #pragma unroll 4
  for (int kk = 0; kk < F1_KS; ++kk){
    float w = p.Wfc[(size_t)(k0+kk)*DH + t];
    #pragma unroll
    for (int rr = 0; rr < F1_ROWS; ++rr) acc[rr] += brow[rr*F1_KS + kk]*w;
  }
  for (int rr = 0; rr < F1_ROWS; ++rr)
    p.part[((size_t)ks*NROW + r0+rr)*DH + t] = acc[rr];
}

// ================= persistent MLP tail: reduce -> fc2 -> fc3 -> final =================
// Coherence-by-construction: block b owns rows 4b..4b+3 in EVERY phase (reads only its
// own plain writes -> same XCD L2); cross-block data (BN stats, barrier) via device atomics.
__device__ __forceinline__ void grid_bar(int* cnt, int target){
  __syncthreads();                       // drains this block's vmem (incl. atomics)
  if (threadIdx.x == 0){
    atomicAdd(cnt, 1);
    while (atomicAdd(cnt, 0) < target) ;
  }
  __syncthreads();
}

__device__ __forceinline__ void fc_layer(const float* in, const float* ps, const float* pq,
    const float* gamma, const float* beta, const float* W, const float* bias,
    float* outG, float* s, float* q, int b, int t, float* row){
  int r0 = b*4;
  const float invM = 1.0f/(float)NROW;
  #pragma unroll
  for (int i = 0; i < 4; ++i){
    int idx = t + i*256;
    int rr = idx >> 8, kk = idx & 255;
    float mu = ps[kk]*invM;
    float var = pq[kk]*invM - mu*mu;
    float rs = rsqrtf(var + BN_EPS);
    float v = in[(size_t)(r0+rr)*DH + kk];
    row[rr*DH + kk] = fmaxf((v-mu)*rs*gamma[kk] + beta[kk], 0.0f);
  }
  __syncthreads();
  float bv = bias[t];
  float a0 = bv, a1 = bv, a2 = bv, a3 = bv;
  #pragma unroll 4
  for (int kk = 0; kk < DH; ++kk){
    float w = W[(size_t)kk*DH + t];
    a0 += row[0*DH+kk]*w; a1 += row[1*DH+kk]*w;
    a2 += row[2*DH+kk]*w; a3 += row[3*DH+kk]*w;
  }
  outG[(size_t)(r0+0)*DH + t] = a0;
  outG[(size_t)(r0+1)*DH + t] = a1;
  outG[(size_t)(r0+2)*DH + t] = a2;
  outG[(size_t)(r0+3)*DH + t] = a3;
  atomicAdd(&s[t], a0+a1+a2+a3);
  atomicAdd(&q[t], a0*a0 + a1*a1 + a2*a2 + a3*a3);
  __syncthreads();   // row[] reused next phase
}

__global__ __launch_bounds__(256, 2) void k_tail(P p){
  __shared__ float row[4*DH];   // 4 KB
  int t = threadIdx.x, b = blockIdx.x;
  // P0: reduce fc1 partials + bias -> G1, stats s1/q1   (rows 4b..4b+3)
  {
    int r0 = b*4;
    float bval = p.bfc[t];
    float ls = 0.f, lq = 0.f;
    for (int rr = 0; rr < 4; ++rr){
      int r = r0+rr;
      float acc = bval;
      for (int sl = 0; sl < F1_NS; ++sl) acc += p.part[((size_t)sl*NROW + r)*DH + t];
      p.G1[(size_t)r*DH + t] = acc;
      ls += acc; lq += acc*acc;
    }
    atomicAdd(&p.s1[t], ls); atomicAdd(&p.q1[t], lq);
  }
  grid_bar(p.bar, TB);
  // P1: fc2 (BN1h+relu, full K)
  fc_layer(p.G1, p.s1, p.q1, p.gbA, p.bbA, p.W2, p.b2, p.G2, p.s2, p.q2, b, t, row);
  grid_bar(p.bar, 2*TB);
  // P2: fc3
  fc_layer(p.G2, p.s2, p.q2, p.gbB, p.bbB, p.W3, p.b3, p.G3, p.s3, p.q3, b, t, row);
  grid_bar(p.bar, 3*TB);
  // P3: final BN3+relu, dot W4, sigmoid (4 rows, one per wave)
  {
    int wave = t>>6, lane = t&63;
    int r = b*4 + wave;
    const float invM = 1.0f/(float)NROW;
    float sum = 0.f;
    #pragma unroll
    for (int j = 0; j < 4; ++j){
      int c = lane + 64*j;
      float mu = p.s3[c]*invM;
      float var = p.q3[c]*invM - mu*mu;
      float rs = rsqrtf(var+BN_EPS);
      float v = p.G3[(size_t)r*DH + c];
      v = fmaxf((v-mu)*rs*p.gbC[c] + p.bbC[c], 0.0f);
      sum += v*p.W4[c];
    }
    #pragma unroll
    for (int off = 32; off > 0; off >>= 1) sum += __shfl_down(sum, off, 64);
    if (lane == 0){
      float z = sum + p.b4[0];
      p.out[r] = 1.0f/(1.0f + expf(-z));
    }
  }
}

extern "C" void kernel_launch(void* const* d_in, const int* in_sizes, int n_in,
                              void* d_out, int out_size, void* d_ws, size_t ws_size,
                              hipStream_t stream) {
  P p;
  p.x     = (const float*)d_in[0];
  p.pg    = (const float*)d_in[1];
  p.neigh = (const float*)d_in[2];
  p.Winit = (const float*)d_in[3];
  p.binit = (const float*)d_in[4];
  p.g1    = (const float*)d_in[5];
  p.be1   = (const float*)d_in[6];
  p.g2    = (const float*)d_in[7];
  p.be2   = (const float*)d_in[8];
  p.Wfc   = (const float*)d_in[9];
  p.bfc   = (const float*)d_in[10];
  p.W2    = (const float*)d_in[11];
  p.b2    = (const float*)d_in[12];
  p.W3    = (const float*)d_in[13];
  p.b3    = (const float*)d_in[14];
  p.W4    = (const float*)d_in[15];
  p.b4    = (const float*)d_in[16];
  p.gbA   = (const float*)d_in[17];
  p.bbA   = (const float*)d_in[18];
  p.gbB   = (const float*)d_in[19];
  p.bbB   = (const float*)d_in[20];
  p.gbC   = (const float*)d_in[21];
  p.bbC   = (const float*)d_in[22];
  p.esrc  = (const int*)d_in[23];
  p.edst  = (const int*)d_in[24];
  p.n2g   = (const int*)d_in[25];
  p.out   = (float*)d_out;

  float* ws = (float*)d_ws;
  size_t off = 0;
  p.hb0 = (unsigned short*)(ws + off); off += (size_t)N_NODES*D/2;
  p.hb1 = (unsigned short*)(ws + off); off += (size_t)N_NODES*D/2;
  p.hb2 = (unsigned short*)(ws + off); off += (size_t)N_NODES*D/2;
  p.zbuf  = ws + off;                 // zero region start
  p.csum1 = ws + off; off += 512;
  p.csq1  = ws + off; off += 512;
  p.csum2 = ws + off; off += 512;
  p.csq2  = ws + off; off += 512;
  p.s1    = ws + off; off += 256;
  p.q1    = ws + off; off += 256;
  p.s2    = ws + off; off += 256;
  p.q2    = ws + off; off += 256;
  p.s3    = ws + off; off += 256;
  p.q3    = ws + off; off += 256;
  p.qemb  = ws + off; off += (size_t)B*D;
  p.bar   = (int*)(ws + off); off += 4;     // end zero region (ZCOUNT floats total)
  p.G1   = ws + off; off += (size_t)NROW*DH;
  p.G2   = ws + off; off += (size_t)NROW*DH;
  p.G3   = ws + off; off += (size_t)NROW*DH;
  p.part = ws + off; off += (size_t)F1_NS*NROW*DH;
  p.degi     = (int*)(ws + off); off += N_NODES;
  p.rowstart = (int*)(ws + off); off += N_NODES + 1;
  p.cursor   = (int*)(ws + off); off += N_NODES;
  p.csr      = (int*)(ws + off); off += N_EDGES;
  p.gstart   = (int*)(ws + off); off += B + 1;

  k_setup<<<64, 256, 0, stream>>>(p);
  k_deg_init<<<DEG_BLOCKS + IM_UNITS, 256, 0, stream>>>(p);
  k_scan<<<1, 256, 0, stream>>>(p);
  k_fill<<<(N_EDGES+255)/256, 256, 0, stream>>>(p);
  k_g1<<<GBLOCKS, 256, 0, stream>>>(p);
  k_g2<<<GBLOCKS, 256, 0, stream>>>(p);
  k_readout<<<512, 256, 0, stream>>>(p);
  k_fc1<<<480, 256, 0, stream>>>(p);
  k_tail<<<TB, 256, 0, stream>>>(p);
}